// Round 5
// baseline (347.539 us; speedup 1.0000x reference)
//
#include <hip/hip_runtime.h>
#include <hip/hip_bf16.h>
#include <math.h>

#define BB 32
#define TT 256
#define ZDIM 32
#define TROWS (TT + 2)   // guarded t dimension: row 0 = t(-1), row 257 = t(256)

typedef float vf4 __attribute__((ext_vector_type(4)));
typedef short short8 __attribute__((ext_vector_type(8)));
typedef short short4v __attribute__((ext_vector_type(4)));
typedef float f32x4 __attribute__((ext_vector_type(4)));

__device__ __forceinline__ float softplus_f(float v) {
    return fmaxf(v, 0.0f) + log1pf(expf(-fabsf(v)));
}

__device__ __forceinline__ unsigned short f2bf(float f) {
    __hip_bfloat16 h = __float2bfloat16(f);
    return *reinterpret_cast<unsigned short*>(&h);
}

// ---------------- weight preconvert + guard-row zeroing ----------------
// W[o][ci][k] fp32 -> Wb[k][o][ci] bf16 (MFMA A-fragment order), and zero the
// t=-1 / t=256 guard rows of the transposed intermediates h0t/h1t.
template<int COUT, int CIN>
__device__ void wconv_one(const float* __restrict__ W, unsigned short* __restrict__ Wb,
                          int tid, int nthreads)
{
    const int n = 3 * COUT * CIN;
    for (int idx = tid; idx < n; idx += nthreads) {
        int ci = idx % CIN;
        int q  = idx / CIN;
        int o  = q % COUT;
        int k  = q / COUT;
        Wb[idx] = f2bf(W[o * (CIN * 3) + ci * 3 + k]);
    }
}

__global__ __launch_bounds__(256)
void wconv_kernel(const float* __restrict__ W0, const float* __restrict__ W1,
                  const float* __restrict__ W2, unsigned short* __restrict__ w0b,
                  unsigned short* __restrict__ w1b, unsigned short* __restrict__ w2b,
                  unsigned short* __restrict__ h0t, unsigned short* __restrict__ h1t)
{
    const int tid = blockIdx.x * blockDim.x + threadIdx.x;
    const int nth = gridDim.x * blockDim.x;
    wconv_one<256, 64>(W0, w0b, tid, nth);
    wconv_one<256, 256>(W1, w1b, tid, nth);
    wconv_one<96, 256>(W2, w2b, tid, nth);
    // zero guard rows: per b, rows 0 and TROWS-1 (256 ch each), short4 writes
    const int ng = BB * 2 * (256 / 4);
    for (int idx = tid; idx < ng; idx += nth) {
        int cv = idx % (256 / 4);
        int q  = idx / (256 / 4);
        int b  = q >> 1;
        int hi = q & 1;
        size_t row = (size_t)(b * TROWS + (hi ? TROWS - 1 : 0)) * 256 + cv * 4;
        short4v z = {0, 0, 0, 0};
        *(short4v*)&h0t[row] = z;
        *(short4v*)&h1t[row] = z;
    }
}

// ---------------- conv1: fp32 x (LDS-staged) -> relu -> h0t transposed ----------------
// out[o][t] = relu(b[o] + sum_ci W[o][ci][k] x[ci][t+k-1]) as 3 shifted GEMMs.
// CIN=64 -> single K step: stage x once (1 barrier total), MFMA, then store
// the C fragment directly transposed: acc[nt][0..3] = 4 consecutive o at fixed
// t -> one 8 B store per fragment into h0t[b][t+1][o]. No epilogue LDS.
// Layouts (m89): A[m=lane&15][ci=quad*8+j], B[ci=quad*8+j][n=lane&15],
// C row = quad*4+reg (o), col = lane&15 (t).
template<int CIN, int COUT, int NW>
__global__ __launch_bounds__(NW * 64, 4)
void conv_stage(const float* __restrict__ xin, const unsigned short* __restrict__ Wb,
                const float* __restrict__ bias, unsigned short* __restrict__ yt)
{
    constexpr int NT    = NW * 64;
    constexpr int OB    = NW * 16;
    constexpr int NTF   = 2;                 // 32-t tile
    constexpr int PVN   = 6;                 // 8-wide stage blocks over [t0-8, t0+39]
    constexpr int XROWS = 48;
    constexpr int XPAD  = 72;                // 144 B rows: aligned b128 reads

    __shared__ __attribute__((aligned(16))) unsigned short xsb[XROWS][XPAD]; // [p][ci]

    const int b    = blockIdx.x;
    const int o0   = blockIdx.y * OB;
    const int t0   = blockIdx.z * 32;
    const int tid  = threadIdx.x;
    const int wv   = tid >> 6;
    const int lane = tid & 63;
    const int l15  = lane & 15;
    const int quad = lane >> 4;

    f32x4 acc[NTF];
    {
        f32x4 bv;
        #pragma unroll
        for (int r = 0; r < 4; ++r) bv[r] = bias[o0 + wv * 16 + quad * 4 + r];
        #pragma unroll
        for (int nt = 0; nt < NTF; ++nt) acc[nt] = bv;
    }

    // stage x tile (single c0 step since CIN == 64)
    for (int idx = tid; idx < CIN * PVN; idx += NT) {
        int ci = idx / PVN;
        int pv = idx - ci * PVN;
        int t8 = t0 - 8 + pv * 8;
        unsigned short v[8];
        if (t8 >= 0 && t8 < TT) {
            const float* xp = xin + (size_t)(b * CIN + ci) * TT + t8;
            f32x4 lo = *(const f32x4*)xp;
            f32x4 hi = *(const f32x4*)(xp + 4);
            #pragma unroll
            for (int j = 0; j < 4; ++j) {
                v[j]     = f2bf(lo[j]);
                v[4 + j] = f2bf(hi[j]);
            }
        } else {
            #pragma unroll
            for (int j = 0; j < 8; ++j) v[j] = 0;
        }
        #pragma unroll
        for (int j = 0; j < 8; ++j) xsb[pv * 8 + j][ci] = v[j];
    }
    __syncthreads();

    const unsigned short* wrow = Wb + (size_t)(o0 + wv * 16 + l15) * CIN + quad * 8;

    #pragma unroll
    for (int ks = 0; ks < 3; ++ks) {
        #pragma unroll
        for (int kc = 0; kc < CIN; kc += 32) {
            short8 af = *(const short8*)(wrow + (size_t)ks * COUT * CIN + kc);
            #pragma unroll
            for (int nt = 0; nt < NTF; ++nt) {
                short8 bf = *(const short8*)&xsb[nt * 16 + l15 + ks + 7][kc + quad * 8];
                acc[nt] = __builtin_amdgcn_mfma_f32_16x16x32_bf16(af, bf, acc[nt], 0, 0, 0);
            }
        }
    }

    // transposed relu epilogue: 8 B store per fragment, direct from registers
    #pragma unroll
    for (int nt = 0; nt < NTF; ++nt) {
        int t = t0 + nt * 16 + l15;
        short4v v;
        #pragma unroll
        for (int r = 0; r < 4; ++r) v[r] = (short)f2bf(fmaxf(acc[nt][r], 0.f));
        *(short4v*)&yt[(size_t)(b * TROWS + t + 1) * COUT + o0 + wv * 16 + quad * 4] = v;
    }
}

// ---------------- conv2/conv3: barrier-free, LDS-free MFMA conv ----------------
// Inputs transposed [b][t+1][CIN] with zeroed guard rows -> B-fragment is one
// aligned 16 B global load (L2/L1-resident, wave-redundant loads hit L1).
// A-fragment direct from Wb (fragment order). No __shared__, no __syncthreads:
// pure load+MFMA stream, pipelined across ~16 waves/CU.
template<int CIN, int COUT, int NW, bool IS_STATS>
__global__ __launch_bounds__(NW * 64, 4)
void conv_flat(const unsigned short* __restrict__ xt, const unsigned short* __restrict__ Wb,
               const float* __restrict__ bias, unsigned short* __restrict__ yt,
               float* __restrict__ out_mu, float* __restrict__ dd,
               float* __restrict__ ss)
{
    constexpr int OB  = NW * 16;
    constexpr int NTF = 2;                  // 32-t tile

    const int b    = blockIdx.x;
    const int o0   = blockIdx.y * OB;
    const int t0   = blockIdx.z * 32;
    const int tid  = threadIdx.x;
    const int wv   = tid >> 6;
    const int lane = tid & 63;
    const int l15  = lane & 15;
    const int quad = lane >> 4;

    f32x4 acc[NTF];
    {
        f32x4 bv;
        #pragma unroll
        for (int r = 0; r < 4; ++r) bv[r] = bias[o0 + wv * 16 + quad * 4 + r];
        #pragma unroll
        for (int nt = 0; nt < NTF; ++nt) acc[nt] = bv;
    }

    const unsigned short* wrow = Wb + (size_t)(o0 + wv * 16 + l15) * CIN + quad * 8;
    // B row for (nt, ks): guarded row = t0 + nt*16 + l15 + ks (= t-1+ks, +1 shift)
    const unsigned short* xrow = xt + (size_t)(b * TROWS + t0 + l15) * CIN + quad * 8;

    #pragma unroll
    for (int c0 = 0; c0 < CIN; c0 += 64) {
        #pragma unroll
        for (int ks = 0; ks < 3; ++ks) {
            #pragma unroll
            for (int kc = 0; kc < 64; kc += 32) {
                short8 af = *(const short8*)(wrow + (size_t)ks * COUT * CIN + c0 + kc);
                #pragma unroll
                for (int nt = 0; nt < NTF; ++nt) {
                    short8 bf = *(const short8*)(xrow + (size_t)(nt * 16 + ks) * CIN + c0 + kc);
                    acc[nt] = __builtin_amdgcn_mfma_f32_16x16x32_bf16(af, bf, acc[nt], 0, 0, 0);
                }
            }
        }
    }

    if constexpr (!IS_STATS) {
        // transposed relu epilogue: 8 B store per fragment
        #pragma unroll
        for (int nt = 0; nt < NTF; ++nt) {
            int t = t0 + nt * 16 + l15;
            short4v v;
            #pragma unroll
            for (int r = 0; r < 4; ++r) v[r] = (short)f2bf(fmaxf(acc[nt][r], 0.f));
            *(short4v*)&yt[(size_t)(b * TROWS + t + 1) * COUT + o0 + wv * 16 + quad * 4] = v;
        }
    } else {
        // stats: o<32 -> mu (fp32); else softplus -> dd (even, +1) / ss (odd)
        #pragma unroll
        for (int nt = 0; nt < NTF; ++nt) {
            int t = t0 + nt * 16 + l15;
            #pragma unroll
            for (int r = 0; r < 4; ++r) {
                int o = o0 + wv * 16 + quad * 4 + r;
                float val = acc[nt][r];
                if (o < ZDIM) {
                    out_mu[(b * ZDIM + o) * TT + t] = val;
                } else {
                    int oc = o - ZDIM;
                    int z  = oc >> 1;
                    float sp = softplus_f(val);
                    if ((oc & 1) == 0) dd[(b * ZDIM + z) * TT + t] = sp + 1.f;
                    else               ss[(b * ZDIM + z) * TT + t] = sp;
                }
            }
        }
    }
}

// ---------------- banded inverse-transpose ----------------
// scale_tril[r,c] = invd[r] * prod_{k=c}^{r-1} t_k (t_k = -s_k/d_k), 0 above diag.
// One 256-thread block per (b,z): 4 waves = 4 row-bands sharing one invd/tt
// load. Ascending product order -> bit-identical to the 1-wave version.
// Write-bound: 268 MB fp32 out, ~43 us floor.
__global__ __launch_bounds__(256)
void tril_kernel(const float* __restrict__ dd, const float* __restrict__ ss,
                 float* __restrict__ out)
{
    __shared__ float invd[TT];
    __shared__ float tt[TT];

    const int bz  = blockIdx.x;
    const int tid = threadIdx.x;

    {
        float d  = dd[bz * TT + tid];
        float s  = ss[bz * TT + tid];
        float iv = 1.0f / d;
        invd[tid] = iv;
        tt[tid]   = -s * iv;
    }
    __syncthreads();

    const int r0 = (tid >> 6) * 64;
    const int c0 = (tid & 63) * 4;

    float p0 = 1.f, p1 = 1.f, p2 = 1.f, p3 = 1.f;
    for (int k = 0; k < r0 - 1; ++k) {
        float tm = tt[k];
        p0 = (k >= c0    ) ? p0 * tm : p0;
        p1 = (k >= c0 + 1) ? p1 * tm : p1;
        p2 = (k >= c0 + 2) ? p2 * tm : p2;
        p3 = (k >= c0 + 3) ? p3 * tm : p3;
    }
    p0 = (c0     < r0) ? p0 : 0.f;
    p1 = (c0 + 1 < r0) ? p1 : 0.f;
    p2 = (c0 + 2 < r0) ? p2 : 0.f;
    p3 = (c0 + 3 < r0) ? p3 : 0.f;

    float* orow = out + (size_t)bz * TT * TT + (size_t)r0 * TT + c0;

    #pragma unroll 2
    for (int r = r0; r < r0 + 64; ++r) {
        float tm = (r > 0) ? tt[r - 1] : 0.0f;
        p0 = (r == c0    ) ? 1.0f : p0 * tm;
        p1 = (r == c0 + 1) ? 1.0f : p1 * tm;
        p2 = (r == c0 + 2) ? 1.0f : p2 * tm;
        p3 = (r == c0 + 3) ? 1.0f : p3 * tm;
        float id = invd[r];
        vf4 v;
        v.x = p0 * id; v.y = p1 * id; v.z = p2 * id; v.w = p3 * id;
        v.x = isfinite(v.x) ? v.x : 0.0f;
        v.y = isfinite(v.y) ? v.y : 0.0f;
        v.z = isfinite(v.z) ? v.z : 0.0f;
        v.w = isfinite(v.w) ? v.w : 0.0f;
        __builtin_nontemporal_store(v, (vf4*)orow);
        orow += TT;
    }
}

extern "C" void kernel_launch(void* const* d_in, const int* in_sizes, int n_in,
                              void* d_out, int out_size, void* d_ws, size_t ws_size,
                              hipStream_t stream)
{
    const float* x  = (const float*)d_in[0];
    const float* W0 = (const float*)d_in[1];
    const float* b0 = (const float*)d_in[2];
    const float* W1 = (const float*)d_in[3];
    const float* b1 = (const float*)d_in[4];
    const float* W2 = (const float*)d_in[5];
    const float* b2 = (const float*)d_in[6];

    float* out = (float*)d_out;
    float* mu  = out;                          // (32,32,256)
    float* st  = out + BB * ZDIM * TT;         // (32,32,256,256)

    // workspace layout: transposed guarded intermediates + fp32 dd/ss + bf16 W
    unsigned short* h0t = (unsigned short*)d_ws;          // 32*258*256 shorts
    unsigned short* h1t = h0t + (size_t)BB * TROWS * 256; // 32*258*256 shorts
    float* dd  = (float*)(h1t + (size_t)BB * TROWS * 256);    // 262,144 floats
    float* ss  = dd + BB * ZDIM * TT;                         // 262,144 floats
    unsigned short* w0b = (unsigned short*)(ss + BB * ZDIM * TT);  // 3*256*64
    unsigned short* w1b = w0b + 3 * 256 * 64;                      // 3*256*256
    unsigned short* w2b = w1b + 3 * 256 * 256;                     // 3*96*256

    // weight preconvert to fragment order + zero h0t/h1t guard rows
    wconv_kernel<<<dim3(256), 256, 0, stream>>>(W0, W1, W2, w0b, w1b, w2b, h0t, h1t);
    // conv1: 64 -> 256, relu (fp32 in, LDS-staged); writes h0t transposed
    conv_stage<64, 256, 4><<<dim3(BB, 4, 8), 256, 0, stream>>>(x, w0b, b0, h0t);
    // conv2: 256 -> 256, relu; barrier-free, LDS-free; h0t -> h1t
    conv_flat<256, 256, 4, false><<<dim3(BB, 4, 8), 256, 0, stream>>>(
        h0t, w1b, b1, h1t, nullptr, nullptr, nullptr);
    // conv3: 256 -> 96, stats; barrier-free, LDS-free; h1t -> mu/dd/ss
    conv_flat<256, 96, 3, true><<<dim3(BB, 2, 8), 192, 0, stream>>>(
        h1t, w2b, b2, nullptr, mu, dd, ss);
    // banded inverse-transpose, write-bound; 1 block = 4 bands per (b,z)
    tril_kernel<<<dim3(BB * ZDIM), 256, 0, stream>>>(dd, ss, st);
}

// Round 6
// 320.251 us; speedup vs baseline: 1.0852x; 1.0852x over previous
//
#include <hip/hip_runtime.h>
#include <hip/hip_bf16.h>
#include <math.h>

#define BB 32
#define TT 256
#define ZDIM 32
#define TROWS (TT + 2)   // guarded t dimension: row 0 = t(-1), row 257 = t(256)

typedef float vf4 __attribute__((ext_vector_type(4)));
typedef short short8 __attribute__((ext_vector_type(8)));
typedef short short4v __attribute__((ext_vector_type(4)));
typedef float f32x4 __attribute__((ext_vector_type(4)));

__device__ __forceinline__ float softplus_f(float v) {
    return fmaxf(v, 0.0f) + log1pf(expf(-fabsf(v)));
}

__device__ __forceinline__ unsigned short f2bf(float f) {
    __hip_bfloat16 h = __float2bfloat16(f);
    return *reinterpret_cast<unsigned short*>(&h);
}

// ---------------- weight preconvert + guard-row zeroing ----------------
// W[o][ci][k] fp32 -> Wb[k][o][ci] bf16 (MFMA A-fragment order), and zero the
// t=-1 / t=256 guard rows of the transposed intermediates h0t/h1t.
template<int COUT, int CIN>
__device__ void wconv_one(const float* __restrict__ W, unsigned short* __restrict__ Wb,
                          int tid, int nthreads)
{
    const int n = 3 * COUT * CIN;
    for (int idx = tid; idx < n; idx += nthreads) {
        int ci = idx % CIN;
        int q  = idx / CIN;
        int o  = q % COUT;
        int k  = q / COUT;
        Wb[idx] = f2bf(W[o * (CIN * 3) + ci * 3 + k]);
    }
}

__global__ __launch_bounds__(256)
void wconv_kernel(const float* __restrict__ W0, const float* __restrict__ W1,
                  const float* __restrict__ W2, unsigned short* __restrict__ w0b,
                  unsigned short* __restrict__ w1b, unsigned short* __restrict__ w2b,
                  unsigned short* __restrict__ h0t, unsigned short* __restrict__ h1t)
{
    const int tid = blockIdx.x * blockDim.x + threadIdx.x;
    const int nth = gridDim.x * blockDim.x;
    wconv_one<256, 64>(W0, w0b, tid, nth);
    wconv_one<256, 256>(W1, w1b, tid, nth);
    wconv_one<96, 256>(W2, w2b, tid, nth);
    // zero guard rows: per b, rows 0 and TROWS-1 (256 ch each), short4 writes
    const int ng = BB * 2 * (256 / 4);
    for (int idx = tid; idx < ng; idx += nth) {
        int cv = idx % (256 / 4);
        int q  = idx / (256 / 4);
        int b  = q >> 1;
        int hi = q & 1;
        size_t row = (size_t)(b * TROWS + (hi ? TROWS - 1 : 0)) * 256 + cv * 4;
        short4v z = {0, 0, 0, 0};
        *(short4v*)&h0t[row] = z;
        *(short4v*)&h1t[row] = z;
    }
}

// ---------------- conv1: fp32 x (LDS-staged, transpose) -> relu -> h0t ----------------
// x comes from the harness [ci][t] fp32, so staging must transpose. CIN=64 ->
// single K step: stage once (1 barrier), direct-global W fragments, MFMA,
// then store the C fragment transposed: acc[nt][0..3] = 4 consecutive o at
// fixed t -> one 8 B store per fragment into h0t[b][t+1][o]. No epilogue LDS.
// Layouts (m89): A[m=lane&15][ci=quad*8+j], B[ci=quad*8+j][n=lane&15],
// C row = quad*4+reg (o), col = lane&15 (t).
template<int CIN, int COUT, int NW>
__global__ __launch_bounds__(NW * 64, 4)
void conv_stage(const float* __restrict__ xin, const unsigned short* __restrict__ Wb,
                const float* __restrict__ bias, unsigned short* __restrict__ yt)
{
    constexpr int NT    = NW * 64;
    constexpr int OB    = NW * 16;
    constexpr int NTF   = 2;                 // 32-t tile
    constexpr int PVN   = 6;                 // 8-wide stage blocks over [t0-8, t0+39]
    constexpr int XROWS = 48;
    constexpr int XPAD  = 72;                // 144 B rows: aligned b128 reads

    __shared__ __attribute__((aligned(16))) unsigned short xsb[XROWS][XPAD]; // [p][ci]

    const int b    = blockIdx.x;
    const int o0   = blockIdx.y * OB;
    const int t0   = blockIdx.z * 32;
    const int tid  = threadIdx.x;
    const int wv   = tid >> 6;
    const int lane = tid & 63;
    const int l15  = lane & 15;
    const int quad = lane >> 4;

    f32x4 acc[NTF];
    {
        f32x4 bv;
        #pragma unroll
        for (int r = 0; r < 4; ++r) bv[r] = bias[o0 + wv * 16 + quad * 4 + r];
        #pragma unroll
        for (int nt = 0; nt < NTF; ++nt) acc[nt] = bv;
    }

    // stage x tile (single c0 step since CIN == 64)
    for (int idx = tid; idx < CIN * PVN; idx += NT) {
        int ci = idx / PVN;
        int pv = idx - ci * PVN;
        int t8 = t0 - 8 + pv * 8;
        unsigned short v[8];
        if (t8 >= 0 && t8 < TT) {
            const float* xp = xin + (size_t)(b * CIN + ci) * TT + t8;
            f32x4 lo = *(const f32x4*)xp;
            f32x4 hi = *(const f32x4*)(xp + 4);
            #pragma unroll
            for (int j = 0; j < 4; ++j) {
                v[j]     = f2bf(lo[j]);
                v[4 + j] = f2bf(hi[j]);
            }
        } else {
            #pragma unroll
            for (int j = 0; j < 8; ++j) v[j] = 0;
        }
        #pragma unroll
        for (int j = 0; j < 8; ++j) xsb[pv * 8 + j][ci] = v[j];
    }
    __syncthreads();

    const unsigned short* wrow = Wb + (size_t)(o0 + wv * 16 + l15) * CIN + quad * 8;

    #pragma unroll
    for (int ks = 0; ks < 3; ++ks) {
        #pragma unroll
        for (int kc = 0; kc < CIN; kc += 32) {
            short8 af = *(const short8*)(wrow + (size_t)ks * COUT * CIN + kc);
            #pragma unroll
            for (int nt = 0; nt < NTF; ++nt) {
                short8 bf = *(const short8*)&xsb[nt * 16 + l15 + ks + 7][kc + quad * 8];
                acc[nt] = __builtin_amdgcn_mfma_f32_16x16x32_bf16(af, bf, acc[nt], 0, 0, 0);
            }
        }
    }

    // transposed relu epilogue: 8 B store per fragment, direct from registers
    #pragma unroll
    for (int nt = 0; nt < NTF; ++nt) {
        int t = t0 + nt * 16 + l15;
        short4v v;
        #pragma unroll
        for (int r = 0; r < 4; ++r) v[r] = (short)f2bf(fmaxf(acc[nt][r], 0.f));
        *(short4v*)&yt[(size_t)(b * TROWS + t + 1) * COUT + o0 + wv * 16 + quad * 4] = v;
    }
}

// ---------------- conv2/conv3: transpose-free staged MFMA conv ----------------
// Input transposed [b][t+1][CIN] (guard rows zeroed) -> staging is a straight
// 2D block copy: 16 B global load -> 16 B LDS write per lane, no scalar
// transpose writes, ONE barrier per block (round 3 had 8 + 48 scalar writes).
// B-fragments then come from LDS (round-3 pattern — the direct-global variant
// regressed +26 us in round 5: per-lane row gathers put L2 latency in front
// of every MFMA). A-fragments direct from global Wb (round-3 win: wave-uniform
// rows, L2-hit). MFMA accumulate order identical to rounds 3/5 (c0 -> ks ->
// kc) -> bit-identical numerics.
template<int CIN, int COUT, int NW, bool IS_STATS>
__global__ __launch_bounds__(NW * 64, 4)
void conv_tile(const unsigned short* __restrict__ xt, const unsigned short* __restrict__ Wb,
               const float* __restrict__ bias, unsigned short* __restrict__ yt,
               float* __restrict__ out_mu, float* __restrict__ dd,
               float* __restrict__ ss)
{
    constexpr int NT    = NW * 64;
    constexpr int OB    = NW * 16;
    constexpr int NTF   = 2;                 // 32-t tile
    constexpr int PROWS = 34;                // guarded rows t0 .. t0+33
    constexpr int XPAD  = CIN + 8;           // 264 shorts = 528 B: 16B-mult, 4-bank row shift

    __shared__ __attribute__((aligned(16))) unsigned short xsb[PROWS][XPAD]; // [p][ci]

    const int b    = blockIdx.x;
    const int o0   = blockIdx.y * OB;
    const int t0   = blockIdx.z * 32;
    const int tid  = threadIdx.x;
    const int wv   = tid >> 6;
    const int lane = tid & 63;
    const int l15  = lane & 15;
    const int quad = lane >> 4;

    f32x4 acc[NTF];
    {
        f32x4 bv;
        #pragma unroll
        for (int r = 0; r < 4; ++r) bv[r] = bias[o0 + wv * 16 + quad * 4 + r];
        #pragma unroll
        for (int nt = 0; nt < NTF; ++nt) acc[nt] = bv;
    }

    // stage [PROWS][CIN] tile: both sides 16 B vector ops, fully coalesced.
    constexpr int CHUNKS = PROWS * (CIN / 8);   // 16 B chunks
    for (int idx = tid; idx < CHUNKS; idx += NT) {
        int c8 = idx & (CIN / 8 - 1);
        int p  = idx / (CIN / 8);
        short8 v = *(const short8*)&xt[(size_t)(b * TROWS + t0 + p) * CIN + c8 * 8];
        *(short8*)&xsb[p][c8 * 8] = v;
    }
    __syncthreads();

    const unsigned short* wrow = Wb + (size_t)(o0 + wv * 16 + l15) * CIN + quad * 8;

    #pragma unroll
    for (int c0 = 0; c0 < CIN; c0 += 64) {
        #pragma unroll
        for (int ks = 0; ks < 3; ++ks) {
            #pragma unroll
            for (int kc = 0; kc < 64; kc += 32) {
                short8 af = *(const short8*)(wrow + (size_t)ks * COUT * CIN + c0 + kc);
                #pragma unroll
                for (int nt = 0; nt < NTF; ++nt) {
                    // B row: guarded t = t0 + nt*16 + l15 + ks -> LDS p = nt*16+l15+ks
                    short8 bf = *(const short8*)&xsb[nt * 16 + l15 + ks][c0 + kc + quad * 8];
                    acc[nt] = __builtin_amdgcn_mfma_f32_16x16x32_bf16(af, bf, acc[nt], 0, 0, 0);
                }
            }
        }
    }

    if constexpr (!IS_STATS) {
        // transposed relu epilogue: 8 B store per fragment, direct from regs
        #pragma unroll
        for (int nt = 0; nt < NTF; ++nt) {
            int t = t0 + nt * 16 + l15;
            short4v v;
            #pragma unroll
            for (int r = 0; r < 4; ++r) v[r] = (short)f2bf(fmaxf(acc[nt][r], 0.f));
            *(short4v*)&yt[(size_t)(b * TROWS + t + 1) * COUT + o0 + wv * 16 + quad * 4] = v;
        }
    } else {
        // stats: o<32 -> mu (fp32); else softplus -> dd (even, +1) / ss (odd)
        #pragma unroll
        for (int nt = 0; nt < NTF; ++nt) {
            int t = t0 + nt * 16 + l15;
            #pragma unroll
            for (int r = 0; r < 4; ++r) {
                int o = o0 + wv * 16 + quad * 4 + r;
                float val = acc[nt][r];
                if (o < ZDIM) {
                    out_mu[(b * ZDIM + o) * TT + t] = val;
                } else {
                    int oc = o - ZDIM;
                    int z  = oc >> 1;
                    float sp = softplus_f(val);
                    if ((oc & 1) == 0) dd[(b * ZDIM + z) * TT + t] = sp + 1.f;
                    else               ss[(b * ZDIM + z) * TT + t] = sp;
                }
            }
        }
    }
}

// ---------------- banded inverse-transpose ----------------
// scale_tril[r,c] = invd[r] * prod_{k=c}^{r-1} t_k (t_k = -s_k/d_k), 0 above diag.
// One 256-thread block per (b,z): 4 waves = 4 row-bands sharing one invd/tt
// load. Ascending product order -> bit-identical to the 1-wave version.
// Write-bound: 268 MB fp32 out, ~43 us floor.
__global__ __launch_bounds__(256)
void tril_kernel(const float* __restrict__ dd, const float* __restrict__ ss,
                 float* __restrict__ out)
{
    __shared__ float invd[TT];
    __shared__ float tt[TT];

    const int bz  = blockIdx.x;
    const int tid = threadIdx.x;

    {
        float d  = dd[bz * TT + tid];
        float s  = ss[bz * TT + tid];
        float iv = 1.0f / d;
        invd[tid] = iv;
        tt[tid]   = -s * iv;
    }
    __syncthreads();

    const int r0 = (tid >> 6) * 64;
    const int c0 = (tid & 63) * 4;

    float p0 = 1.f, p1 = 1.f, p2 = 1.f, p3 = 1.f;
    for (int k = 0; k < r0 - 1; ++k) {
        float tm = tt[k];
        p0 = (k >= c0    ) ? p0 * tm : p0;
        p1 = (k >= c0 + 1) ? p1 * tm : p1;
        p2 = (k >= c0 + 2) ? p2 * tm : p2;
        p3 = (k >= c0 + 3) ? p3 * tm : p3;
    }
    p0 = (c0     < r0) ? p0 : 0.f;
    p1 = (c0 + 1 < r0) ? p1 : 0.f;
    p2 = (c0 + 2 < r0) ? p2 : 0.f;
    p3 = (c0 + 3 < r0) ? p3 : 0.f;

    float* orow = out + (size_t)bz * TT * TT + (size_t)r0 * TT + c0;

    #pragma unroll 2
    for (int r = r0; r < r0 + 64; ++r) {
        float tm = (r > 0) ? tt[r - 1] : 0.0f;
        p0 = (r == c0    ) ? 1.0f : p0 * tm;
        p1 = (r == c0 + 1) ? 1.0f : p1 * tm;
        p2 = (r == c0 + 2) ? 1.0f : p2 * tm;
        p3 = (r == c0 + 3) ? 1.0f : p3 * tm;
        float id = invd[r];
        vf4 v;
        v.x = p0 * id; v.y = p1 * id; v.z = p2 * id; v.w = p3 * id;
        v.x = isfinite(v.x) ? v.x : 0.0f;
        v.y = isfinite(v.y) ? v.y : 0.0f;
        v.z = isfinite(v.z) ? v.z : 0.0f;
        v.w = isfinite(v.w) ? v.w : 0.0f;
        __builtin_nontemporal_store(v, (vf4*)orow);
        orow += TT;
    }
}

extern "C" void kernel_launch(void* const* d_in, const int* in_sizes, int n_in,
                              void* d_out, int out_size, void* d_ws, size_t ws_size,
                              hipStream_t stream)
{
    const float* x  = (const float*)d_in[0];
    const float* W0 = (const float*)d_in[1];
    const float* b0 = (const float*)d_in[2];
    const float* W1 = (const float*)d_in[3];
    const float* b1 = (const float*)d_in[4];
    const float* W2 = (const float*)d_in[5];
    const float* b2 = (const float*)d_in[6];

    float* out = (float*)d_out;
    float* mu  = out;                          // (32,32,256)
    float* st  = out + BB * ZDIM * TT;         // (32,32,256,256)

    // workspace layout: transposed guarded intermediates + fp32 dd/ss + bf16 W
    unsigned short* h0t = (unsigned short*)d_ws;          // 32*258*256 shorts
    unsigned short* h1t = h0t + (size_t)BB * TROWS * 256; // 32*258*256 shorts
    float* dd  = (float*)(h1t + (size_t)BB * TROWS * 256);    // 262,144 floats
    float* ss  = dd + BB * ZDIM * TT;                         // 262,144 floats
    unsigned short* w0b = (unsigned short*)(ss + BB * ZDIM * TT);  // 3*256*64
    unsigned short* w1b = w0b + 3 * 256 * 64;                      // 3*256*256
    unsigned short* w2b = w1b + 3 * 256 * 256;                     // 3*96*256

    // weight preconvert to fragment order + zero h0t/h1t guard rows
    wconv_kernel<<<dim3(256), 256, 0, stream>>>(W0, W1, W2, w0b, w1b, w2b, h0t, h1t);
    // conv1: 64 -> 256, relu (fp32 in, LDS-staged); writes h0t transposed
    conv_stage<64, 256, 4><<<dim3(BB, 4, 8), 256, 0, stream>>>(x, w0b, b0, h0t);
    // conv2: 256 -> 256, relu; transpose-free staged tile; h0t -> h1t
    conv_tile<256, 256, 4, false><<<dim3(BB, 4, 8), 256, 0, stream>>>(
        h0t, w1b, b1, h1t, nullptr, nullptr, nullptr);
    // conv3: 256 -> 96, stats; transpose-free staged tile; h1t -> mu/dd/ss
    conv_tile<256, 96, 3, true><<<dim3(BB, 2, 8), 192, 0, stream>>>(
        h1t, w2b, b2, nullptr, mu, dd, ss);
    // banded inverse-transpose, write-bound; 1 block = 4 bands per (b,z)
    tril_kernel<<<dim3(BB * ZDIM), 256, 0, stream>>>(dd, ss, st);
}

// Round 7
// 311.861 us; speedup vs baseline: 1.1144x; 1.0269x over previous
//
#include <hip/hip_runtime.h>
#include <hip/hip_bf16.h>
#include <math.h>

#define BB 32
#define TT 256
#define ZDIM 32

typedef float vf4 __attribute__((ext_vector_type(4)));
typedef short short8 __attribute__((ext_vector_type(8)));
typedef short short4v __attribute__((ext_vector_type(4)));
typedef float f32x4 __attribute__((ext_vector_type(4)));

__device__ __forceinline__ float softplus_f(float v) {
    return fmaxf(v, 0.0f) + log1pf(expf(-fabsf(v)));
}

__device__ __forceinline__ unsigned short f2bf(float f) {
    __hip_bfloat16 h = __float2bfloat16(f);
    return *reinterpret_cast<unsigned short*>(&h);
}

// ---------------- weight preconvert: W[o][ci][k] fp32 -> Wb[k][o][ci] bf16 ----------------
template<int COUT, int CIN>
__device__ void wconv_one(const float* __restrict__ W, unsigned short* __restrict__ Wb,
                          int tid, int nthreads)
{
    const int n = 3 * COUT * CIN;
    for (int idx = tid; idx < n; idx += nthreads) {
        int ci = idx % CIN;
        int q  = idx / CIN;
        int o  = q % COUT;
        int k  = q / COUT;
        Wb[idx] = f2bf(W[o * (CIN * 3) + ci * 3 + k]);
    }
}

__global__ __launch_bounds__(256)
void wconv_kernel(const float* __restrict__ W0, const float* __restrict__ W1,
                  const float* __restrict__ W2, unsigned short* __restrict__ w0b,
                  unsigned short* __restrict__ w1b, unsigned short* __restrict__ w2b)
{
    const int tid = blockIdx.x * blockDim.x + threadIdx.x;
    const int nth = gridDim.x * blockDim.x;
    wconv_one<256, 64>(W0, w0b, tid, nth);
    wconv_one<256, 256>(W1, w1b, tid, nth);
    wconv_one<96, 256>(W2, w2b, tid, nth);
}

// ---------------- fused conv1+conv2+conv3 ----------------
// One block per (b, 32-t range). Halo recompute: layer1 on t in [t0-8,t0+40)
// (3 frags), layer2 on [t0-1,t0+32] (3 frags at offsets {-1,15,17}, overlap
// writes duplicate identical values), layer3 on [t0,t0+32) (2 frags).
// All intermediates in LDS (bf16, transposed [t][ch]); 3 barriers total; no
// global intermediate traffic. SAME-padding: x staged zero outside [0,256);
// h0s/h1s writes masked to zero for t outside [0,256) (replaces guard rows).
// Weights direct from global Wb[k][o][ci] (round-3-proven wave-row pattern);
// B-fragments from LDS (round-5 lesson: x-gather from global regresses).
// Per-acc MFMA order c0 -> ks -> kc identical to the split kernels ->
// bit-identical numerics.
// Layouts (m89): A[m=lane&15][ci=quad*8+j], B[ci=quad*8+j][n=lane&15],
// C row = quad*4+reg (o), col = lane&15 (t).
__global__ __launch_bounds__(512, 1)
void fused_conv(const float* __restrict__ x,
                const unsigned short* __restrict__ w0b,
                const unsigned short* __restrict__ w1b,
                const unsigned short* __restrict__ w2b,
                const float* __restrict__ b0, const float* __restrict__ b1,
                const float* __restrict__ b2,
                float* __restrict__ mu, float* __restrict__ dd,
                float* __restrict__ ss)
{
    constexpr int XPAD = 72;    // 144 B rows (aligned b128 reads)
    constexpr int HPAD = 264;   // 528 B rows (aligned, 4-dw bank shift per row)

    __shared__ __attribute__((aligned(16))) unsigned short xsb[64][XPAD]; // x: [t-(t0-16)][ci]
    __shared__ __attribute__((aligned(16))) unsigned short h0s[48][HPAD]; // h0: [t-(t0-8)][o]
    __shared__ __attribute__((aligned(16))) unsigned short h1s[34][HPAD]; // h1: [t-(t0-1)][o]

    const int b    = blockIdx.x;
    const int t0   = blockIdx.y * 32;
    const int tid  = threadIdx.x;
    const int wv   = tid >> 6;
    const int lane = tid & 63;
    const int l15  = lane & 15;
    const int quad = lane >> 4;

    // ---- stage x: 64 rows [t0-16, t0+48) x 64 ci. wave wv stages pv-block wv
    // (8 consecutive t). Per lane: one ci row, f32x4 x2 load, 8 LDS writes
    // (contiguous across lanes -> ~2-way max). bf16 zero == 0.
    {
        const int ci = lane;
        const int t8 = t0 - 16 + wv * 8;
        unsigned short v[8];
        if (t8 >= 0 && t8 < TT) {
            const float* xp = x + (size_t)(b * 64 + ci) * TT + t8;
            f32x4 lo = *(const f32x4*)xp;
            f32x4 hi = *(const f32x4*)(xp + 4);
            #pragma unroll
            for (int j = 0; j < 4; ++j) { v[j] = f2bf(lo[j]); v[4 + j] = f2bf(hi[j]); }
        } else {
            #pragma unroll
            for (int j = 0; j < 8; ++j) v[j] = 0;
        }
        #pragma unroll
        for (int j = 0; j < 8; ++j) xsb[wv * 8 + j][ci] = v[j];
    }
    __syncthreads();

    // ---- layer1: wave wv owns o-tiles {wv, wv+8}, 3 t-frags at t0-8+nt*16.
    // Reads x at t+ks-1 -> xsb row nt*16 + l15 + ks + 7 (range [7,56]).
    {
        f32x4 a1[2][3];
        #pragma unroll
        for (int oi = 0; oi < 2; ++oi) {
            f32x4 bv;
            #pragma unroll
            for (int r = 0; r < 4; ++r) bv[r] = b0[(wv + 8 * oi) * 16 + quad * 4 + r];
            #pragma unroll
            for (int nt = 0; nt < 3; ++nt) a1[oi][nt] = bv;
        }
        const unsigned short* w0r0 = w0b + (size_t)(wv * 16 + l15) * 64 + quad * 8;
        const unsigned short* w0r1 = w0b + (size_t)((wv + 8) * 16 + l15) * 64 + quad * 8;
        #pragma unroll
        for (int ks = 0; ks < 3; ++ks) {
            #pragma unroll
            for (int kc = 0; kc < 64; kc += 32) {
                short8 af0 = *(const short8*)(w0r0 + (size_t)ks * 256 * 64 + kc);
                short8 af1 = *(const short8*)(w0r1 + (size_t)ks * 256 * 64 + kc);
                #pragma unroll
                for (int nt = 0; nt < 3; ++nt) {
                    short8 bf = *(const short8*)&xsb[nt * 16 + l15 + ks + 7][kc + quad * 8];
                    a1[0][nt] = __builtin_amdgcn_mfma_f32_16x16x32_bf16(af0, bf, a1[0][nt], 0, 0, 0);
                    a1[1][nt] = __builtin_amdgcn_mfma_f32_16x16x32_bf16(af1, bf, a1[1][nt], 0, 0, 0);
                }
            }
        }
        // h0s write: row p = nt*16+l15 (t = t0-8+p), col o; relu+bf16, masked
        // to zero outside [0,TT) = SAME padding for layer2.
        #pragma unroll
        for (int oi = 0; oi < 2; ++oi) {
            #pragma unroll
            for (int nt = 0; nt < 3; ++nt) {
                int p = nt * 16 + l15;
                int t = t0 - 8 + p;
                bool ok = (t >= 0) && (t < TT);
                short4v v;
                #pragma unroll
                for (int r = 0; r < 4; ++r)
                    v[r] = ok ? (short)f2bf(fmaxf(a1[oi][nt][r], 0.f)) : (short)0;
                *(short4v*)&h0s[p][(wv + 8 * oi) * 16 + quad * 4] = v;
            }
        }
    }
    __syncthreads();

    // ---- layer2: o-tiles {wv, wv+8}, 3 t-frags at t0 + {-1,15,17}.
    // Reads h0 at t+ks-1 -> h0s row l15 + ks + {6,22,24}[nt] (range [6,41]).
    {
        f32x4 a2[2][3];
        #pragma unroll
        for (int oi = 0; oi < 2; ++oi) {
            f32x4 bv;
            #pragma unroll
            for (int r = 0; r < 4; ++r) bv[r] = b1[(wv + 8 * oi) * 16 + quad * 4 + r];
            #pragma unroll
            for (int nt = 0; nt < 3; ++nt) a2[oi][nt] = bv;
        }
        const unsigned short* w1r0 = w1b + (size_t)(wv * 16 + l15) * 256 + quad * 8;
        const unsigned short* w1r1 = w1b + (size_t)((wv + 8) * 16 + l15) * 256 + quad * 8;
        #pragma unroll
        for (int c0 = 0; c0 < 256; c0 += 64) {
            #pragma unroll
            for (int ks = 0; ks < 3; ++ks) {
                #pragma unroll
                for (int kc = 0; kc < 64; kc += 32) {
                    short8 af0 = *(const short8*)(w1r0 + (size_t)ks * 256 * 256 + c0 + kc);
                    short8 af1 = *(const short8*)(w1r1 + (size_t)ks * 256 * 256 + c0 + kc);
                    #pragma unroll
                    for (int nt = 0; nt < 3; ++nt) {
                        constexpr int F2[3] = {6, 22, 24};
                        short8 bf = *(const short8*)&h0s[F2[nt] + l15 + ks][c0 + kc + quad * 8];
                        a2[0][nt] = __builtin_amdgcn_mfma_f32_16x16x32_bf16(af0, bf, a2[0][nt], 0, 0, 0);
                        a2[1][nt] = __builtin_amdgcn_mfma_f32_16x16x32_bf16(af1, bf, a2[1][nt], 0, 0, 0);
                    }
                }
            }
        }
        // h1s write: rows {0,16,18}+l15 (t = t0+{-1,15,17}+l15); overlap rows
        // get duplicate identical writes (same math) - benign. Masked padding.
        #pragma unroll
        for (int oi = 0; oi < 2; ++oi) {
            #pragma unroll
            for (int nt = 0; nt < 3; ++nt) {
                constexpr int P2[3]  = {0, 16, 18};
                constexpr int TO2[3] = {-1, 15, 17};
                int p = P2[nt] + l15;
                int t = t0 + TO2[nt] + l15;
                bool ok = (t >= 0) && (t < TT);
                short4v v;
                #pragma unroll
                for (int r = 0; r < 4; ++r)
                    v[r] = ok ? (short)f2bf(fmaxf(a2[oi][nt][r], 0.f)) : (short)0;
                *(short4v*)&h1s[p][(wv + 8 * oi) * 16 + quad * 4] = v;
            }
        }
    }
    __syncthreads();

    // ---- layer3 (stats): 12 tiles (6 o-tiles x 2 t-frags); waves 0-3 take 2,
    // waves 4-7 take 1. Reads h1 at t+ks-1 -> h1s row nt*16 + l15 + ks.
    {
        const int nu = (wv < 4) ? 2 : 1;
        for (int i = 0; i < nu; ++i) {
            const int u  = wv + 8 * i;
            const int ot = u % 6;
            const int nt = u / 6;
            f32x4 a3;
            #pragma unroll
            for (int r = 0; r < 4; ++r) a3[r] = b2[ot * 16 + quad * 4 + r];
            const unsigned short* w2r = w2b + (size_t)(ot * 16 + l15) * 256 + quad * 8;
            #pragma unroll
            for (int c0 = 0; c0 < 256; c0 += 64) {
                #pragma unroll
                for (int ks = 0; ks < 3; ++ks) {
                    #pragma unroll
                    for (int kc = 0; kc < 64; kc += 32) {
                        short8 af = *(const short8*)(w2r + (size_t)ks * 96 * 256 + c0 + kc);
                        short8 bf = *(const short8*)&h1s[nt * 16 + l15 + ks][c0 + kc + quad * 8];
                        a3 = __builtin_amdgcn_mfma_f32_16x16x32_bf16(af, bf, a3, 0, 0, 0);
                    }
                }
            }
            const int t = t0 + nt * 16 + l15;
            #pragma unroll
            for (int r = 0; r < 4; ++r) {
                int o = ot * 16 + quad * 4 + r;
                float val = a3[r];
                if (o < ZDIM) {
                    mu[(b * ZDIM + o) * TT + t] = val;
                } else {
                    int oc = o - ZDIM;
                    int z  = oc >> 1;
                    float sp = softplus_f(val);
                    if ((oc & 1) == 0) dd[(b * ZDIM + z) * TT + t] = sp + 1.f;
                    else               ss[(b * ZDIM + z) * TT + t] = sp;
                }
            }
        }
    }
}

// ---------------- banded inverse-transpose ----------------
// scale_tril[r,c] = invd[r] * prod_{k=c}^{r-1} t_k (t_k = -s_k/d_k), 0 above diag.
// One 256-thread block per (b,z): 4 waves = 4 row-bands sharing one invd/tt
// load. Ascending product order -> bit-identical to the 1-wave version.
// Write-bound: 268 MB fp32 out, ~43 us floor.
__global__ __launch_bounds__(256)
void tril_kernel(const float* __restrict__ dd, const float* __restrict__ ss,
                 float* __restrict__ out)
{
    __shared__ float invd[TT];
    __shared__ float tt[TT];

    const int bz  = blockIdx.x;
    const int tid = threadIdx.x;

    {
        float d  = dd[bz * TT + tid];
        float s  = ss[bz * TT + tid];
        float iv = 1.0f / d;
        invd[tid] = iv;
        tt[tid]   = -s * iv;
    }
    __syncthreads();

    const int r0 = (tid >> 6) * 64;
    const int c0 = (tid & 63) * 4;

    float p0 = 1.f, p1 = 1.f, p2 = 1.f, p3 = 1.f;
    for (int k = 0; k < r0 - 1; ++k) {
        float tm = tt[k];
        p0 = (k >= c0    ) ? p0 * tm : p0;
        p1 = (k >= c0 + 1) ? p1 * tm : p1;
        p2 = (k >= c0 + 2) ? p2 * tm : p2;
        p3 = (k >= c0 + 3) ? p3 * tm : p3;
    }
    p0 = (c0     < r0) ? p0 : 0.f;
    p1 = (c0 + 1 < r0) ? p1 : 0.f;
    p2 = (c0 + 2 < r0) ? p2 : 0.f;
    p3 = (c0 + 3 < r0) ? p3 : 0.f;

    float* orow = out + (size_t)bz * TT * TT + (size_t)r0 * TT + c0;

    #pragma unroll 2
    for (int r = r0; r < r0 + 64; ++r) {
        float tm = (r > 0) ? tt[r - 1] : 0.0f;
        p0 = (r == c0    ) ? 1.0f : p0 * tm;
        p1 = (r == c0 + 1) ? 1.0f : p1 * tm;
        p2 = (r == c0 + 2) ? 1.0f : p2 * tm;
        p3 = (r == c0 + 3) ? 1.0f : p3 * tm;
        float id = invd[r];
        vf4 v;
        v.x = p0 * id; v.y = p1 * id; v.z = p2 * id; v.w = p3 * id;
        v.x = isfinite(v.x) ? v.x : 0.0f;
        v.y = isfinite(v.y) ? v.y : 0.0f;
        v.z = isfinite(v.z) ? v.z : 0.0f;
        v.w = isfinite(v.w) ? v.w : 0.0f;
        __builtin_nontemporal_store(v, (vf4*)orow);
        orow += TT;
    }
}

extern "C" void kernel_launch(void* const* d_in, const int* in_sizes, int n_in,
                              void* d_out, int out_size, void* d_ws, size_t ws_size,
                              hipStream_t stream)
{
    const float* x  = (const float*)d_in[0];
    const float* W0 = (const float*)d_in[1];
    const float* b0 = (const float*)d_in[2];
    const float* W1 = (const float*)d_in[3];
    const float* b1 = (const float*)d_in[4];
    const float* W2 = (const float*)d_in[5];
    const float* b2 = (const float*)d_in[6];

    float* out = (float*)d_out;
    float* mu  = out;                          // (32,32,256)
    float* st  = out + BB * ZDIM * TT;         // (32,32,256,256)

    // workspace: fp32 dd/ss + bf16 fragment-order weights (no intermediates)
    float* dd = (float*)d_ws;                              // 262,144 floats
    float* ss = dd + BB * ZDIM * TT;                       // 262,144 floats
    unsigned short* w0b = (unsigned short*)(ss + BB * ZDIM * TT);  // 3*256*64
    unsigned short* w1b = w0b + 3 * 256 * 64;                      // 3*256*256
    unsigned short* w2b = w1b + 3 * 256 * 256;                     // 3*96*256

    // weight preconvert to fragment order
    wconv_kernel<<<dim3(256), 256, 0, stream>>>(W0, W1, W2, w0b, w1b, w2b);
    // fused conv1+conv2+conv3: 256 blocks (1/CU), 8 waves, 3 barriers
    fused_conv<<<dim3(BB, 8), 512, 0, stream>>>(
        x, w0b, w1b, w2b, b0, b1, b2, mu, dd, ss);
    // banded inverse-transpose, write-bound; 1 block = 4 bands per (b,z)
    tril_kernel<<<dim3(BB * ZDIM), 256, 0, stream>>>(dd, ss, st);
}

// Round 8
// 303.417 us; speedup vs baseline: 1.1454x; 1.0278x over previous
//
#include <hip/hip_runtime.h>
#include <hip/hip_bf16.h>
#include <math.h>

#define BB 32
#define TT 256
#define ZDIM 32

typedef float vf4 __attribute__((ext_vector_type(4)));
typedef short short8 __attribute__((ext_vector_type(8)));
typedef short short4v __attribute__((ext_vector_type(4)));
typedef float f32x4 __attribute__((ext_vector_type(4)));

__device__ __forceinline__ float softplus_f(float v) {
    return fmaxf(v, 0.0f) + log1pf(expf(-fabsf(v)));
}

__device__ __forceinline__ unsigned short f2bf(float f) {
    __hip_bfloat16 h = __float2bfloat16(f);
    return *reinterpret_cast<unsigned short*>(&h);
}

// ---------------- weight preconvert: blocked fragment layout ----------------
// W[o][ci][k] fp32 -> Wb[ks][otile][kch][lane][8] bf16, where a wave's A
// fragment for (ks, otile, 32-ci chunk kch) is the contiguous 1 KB block
// Wb + blk*512 + lane*8  (lane = quad*16+l15, o = otile*16+l15,
// ci = kch*32 + quad*8 + j). af loads become single coalesced bursts with a
// linear address bump instead of 16-row x 512 B gathers.
template<int COUT, int CIN>
__device__ void wconv_frag(const float* __restrict__ W, unsigned short* __restrict__ Wb,
                           int tid, int nthreads)
{
    const int n = 3 * COUT * CIN;
    for (int idx = tid; idx < n; idx += nthreads) {
        int j     = idx & 7;
        int lane  = (idx >> 3) & 63;
        int rest  = idx >> 9;                 // (ks*(COUT/16)+ot)*(CIN/32)+kch
        int kch   = rest % (CIN / 32);
        int rest2 = rest / (CIN / 32);
        int ot    = rest2 % (COUT / 16);
        int ks    = rest2 / (COUT / 16);
        int o  = ot * 16 + (lane & 15);
        int ci = kch * 32 + (lane >> 4) * 8 + j;
        Wb[idx] = f2bf(W[(o * CIN + ci) * 3 + ks]);
    }
}

__global__ __launch_bounds__(256)
void wconv_kernel(const float* __restrict__ W0, const float* __restrict__ W1,
                  const float* __restrict__ W2, unsigned short* __restrict__ w0b,
                  unsigned short* __restrict__ w1b, unsigned short* __restrict__ w2b)
{
    const int tid = blockIdx.x * blockDim.x + threadIdx.x;
    const int nth = gridDim.x * blockDim.x;
    wconv_frag<256, 64>(W0, w0b, tid, nth);
    wconv_frag<256, 256>(W1, w1b, tid, nth);
    wconv_frag<96, 256>(W2, w2b, tid, nth);
}

// ---------------- fused conv1+conv2+conv3 ----------------
// Geometry identical to round 7 (one block per (b, 32-t range), 8 waves,
// 3 barriers, all intermediates in LDS). Round-8 changes are codegen-only:
// (1) #pragma unroll 1 on the c0 loops (bounds live VGPRs; the full unroll
// risked spill-to-scratch / JIT loads exposing L2 latency 24x per wave);
// (2) af loads from the blocked fragment layout: one contiguous 1 KB/wave
// coalesced load, af address = base + blk*512 + lane*8.
// Per-acc MFMA order (c0 -> ks -> kc) unchanged -> bit-identical numerics.
// Layouts (m89): A[m=lane&15][ci=quad*8+j], B[ci=quad*8+j][n=lane&15],
// C row = quad*4+reg (o), col = lane&15 (t).
__global__ __launch_bounds__(512, 1)
void fused_conv(const float* __restrict__ x,
                const unsigned short* __restrict__ w0b,
                const unsigned short* __restrict__ w1b,
                const unsigned short* __restrict__ w2b,
                const float* __restrict__ b0, const float* __restrict__ b1,
                const float* __restrict__ b2,
                float* __restrict__ mu, float* __restrict__ dd,
                float* __restrict__ ss)
{
    constexpr int XPAD = 72;    // 144 B rows (aligned b128 reads)
    constexpr int HPAD = 264;   // 528 B rows (aligned; b128 reads at 8-cyc floor)

    __shared__ __attribute__((aligned(16))) unsigned short xsb[64][XPAD]; // x: [t-(t0-16)][ci]
    __shared__ __attribute__((aligned(16))) unsigned short h0s[48][HPAD]; // h0: [t-(t0-8)][o]
    __shared__ __attribute__((aligned(16))) unsigned short h1s[34][HPAD]; // h1: [t-(t0-1)][o]

    const int b    = blockIdx.x;
    const int t0   = blockIdx.y * 32;
    const int tid  = threadIdx.x;
    const int wv   = tid >> 6;
    const int lane = tid & 63;
    const int l15  = lane & 15;
    const int quad = lane >> 4;

    // ---- stage x: 64 rows [t0-16, t0+48) x 64 ci. wave wv stages pv-block wv.
    {
        const int ci = lane;
        const int t8 = t0 - 16 + wv * 8;
        unsigned short v[8];
        if (t8 >= 0 && t8 < TT) {
            const float* xp = x + (size_t)(b * 64 + ci) * TT + t8;
            f32x4 lo = *(const f32x4*)xp;
            f32x4 hi = *(const f32x4*)(xp + 4);
            #pragma unroll
            for (int j = 0; j < 4; ++j) { v[j] = f2bf(lo[j]); v[4 + j] = f2bf(hi[j]); }
        } else {
            #pragma unroll
            for (int j = 0; j < 8; ++j) v[j] = 0;
        }
        #pragma unroll
        for (int j = 0; j < 8; ++j) xsb[wv * 8 + j][ci] = v[j];
    }
    __syncthreads();

    // ---- layer1: wave wv owns o-tiles {wv, wv+8}, 3 t-frags at t0-8+nt*16.
    // Reads x at t+ks-1 -> xsb row nt*16 + l15 + ks + 7 (range [7,56]).
    {
        f32x4 a1[2][3];
        #pragma unroll
        for (int oi = 0; oi < 2; ++oi) {
            f32x4 bv;
            #pragma unroll
            for (int r = 0; r < 4; ++r) bv[r] = b0[(wv + 8 * oi) * 16 + quad * 4 + r];
            #pragma unroll
            for (int nt = 0; nt < 3; ++nt) a1[oi][nt] = bv;
        }
        // layer1 blocks: blk = (ks*16 + ot)*2 + (kc>>5); COUT/16=16, CIN/32=2
        #pragma unroll
        for (int ks = 0; ks < 3; ++ks) {
            #pragma unroll
            for (int kc = 0; kc < 64; kc += 32) {
                short8 af0 = *(const short8*)(w0b + (size_t)(((ks * 16 + wv) * 2) + (kc >> 5)) * 512 + lane * 8);
                short8 af1 = *(const short8*)(w0b + (size_t)(((ks * 16 + wv + 8) * 2) + (kc >> 5)) * 512 + lane * 8);
                #pragma unroll
                for (int nt = 0; nt < 3; ++nt) {
                    short8 bf = *(const short8*)&xsb[nt * 16 + l15 + ks + 7][kc + quad * 8];
                    a1[0][nt] = __builtin_amdgcn_mfma_f32_16x16x32_bf16(af0, bf, a1[0][nt], 0, 0, 0);
                    a1[1][nt] = __builtin_amdgcn_mfma_f32_16x16x32_bf16(af1, bf, a1[1][nt], 0, 0, 0);
                }
            }
        }
        // h0s write: row p = nt*16+l15 (t = t0-8+p); relu+bf16, masked to zero
        // outside [0,TT) = SAME padding for layer2.
        #pragma unroll
        for (int oi = 0; oi < 2; ++oi) {
            #pragma unroll
            for (int nt = 0; nt < 3; ++nt) {
                int p = nt * 16 + l15;
                int t = t0 - 8 + p;
                bool ok = (t >= 0) && (t < TT);
                short4v v;
                #pragma unroll
                for (int r = 0; r < 4; ++r)
                    v[r] = ok ? (short)f2bf(fmaxf(a1[oi][nt][r], 0.f)) : (short)0;
                *(short4v*)&h0s[p][(wv + 8 * oi) * 16 + quad * 4] = v;
            }
        }
    }
    __syncthreads();

    // ---- layer2: o-tiles {wv, wv+8}, 3 t-frags at t0 + {-1,15,17}.
    // Reads h0 at t+ks-1 -> h0s row l15 + ks + {6,22,24}[nt] (range [6,41]).
    {
        f32x4 a2[2][3];
        #pragma unroll
        for (int oi = 0; oi < 2; ++oi) {
            f32x4 bv;
            #pragma unroll
            for (int r = 0; r < 4; ++r) bv[r] = b1[(wv + 8 * oi) * 16 + quad * 4 + r];
            #pragma unroll
            for (int nt = 0; nt < 3; ++nt) a2[oi][nt] = bv;
        }
        // layer2 blocks: blk = (ks*16 + ot)*8 + ((c0+kc)>>5); CIN/32=8
        #pragma unroll 1
        for (int c0 = 0; c0 < 256; c0 += 64) {
            #pragma unroll
            for (int ks = 0; ks < 3; ++ks) {
                #pragma unroll
                for (int kc = 0; kc < 64; kc += 32) {
                    short8 af0 = *(const short8*)(w1b + (size_t)((ks * 16 + wv) * 8 + ((c0 + kc) >> 5)) * 512 + lane * 8);
                    short8 af1 = *(const short8*)(w1b + (size_t)((ks * 16 + wv + 8) * 8 + ((c0 + kc) >> 5)) * 512 + lane * 8);
                    #pragma unroll
                    for (int nt = 0; nt < 3; ++nt) {
                        constexpr int F2[3] = {6, 22, 24};
                        short8 bf = *(const short8*)&h0s[F2[nt] + l15 + ks][c0 + kc + quad * 8];
                        a2[0][nt] = __builtin_amdgcn_mfma_f32_16x16x32_bf16(af0, bf, a2[0][nt], 0, 0, 0);
                        a2[1][nt] = __builtin_amdgcn_mfma_f32_16x16x32_bf16(af1, bf, a2[1][nt], 0, 0, 0);
                    }
                }
            }
        }
        // h1s write: rows {0,16,18}+l15 (t = t0+{-1,15,17}+l15); overlap rows
        // duplicate identical values - benign. Masked padding.
        #pragma unroll
        for (int oi = 0; oi < 2; ++oi) {
            #pragma unroll
            for (int nt = 0; nt < 3; ++nt) {
                constexpr int P2[3]  = {0, 16, 18};
                constexpr int TO2[3] = {-1, 15, 17};
                int p = P2[nt] + l15;
                int t = t0 + TO2[nt] + l15;
                bool ok = (t >= 0) && (t < TT);
                short4v v;
                #pragma unroll
                for (int r = 0; r < 4; ++r)
                    v[r] = ok ? (short)f2bf(fmaxf(a2[oi][nt][r], 0.f)) : (short)0;
                *(short4v*)&h1s[p][(wv + 8 * oi) * 16 + quad * 4] = v;
            }
        }
    }
    __syncthreads();

    // ---- layer3 (stats): 12 tiles (6 o-tiles x 2 t-frags); waves 0-3 take 2,
    // waves 4-7 take 1. Reads h1 at t+ks-1 -> h1s row nt*16 + l15 + ks.
    {
        const int nu = (wv < 4) ? 2 : 1;
        for (int i = 0; i < nu; ++i) {
            const int u  = wv + 8 * i;
            const int ot = u % 6;
            const int nt = u / 6;
            f32x4 a3;
            #pragma unroll
            for (int r = 0; r < 4; ++r) a3[r] = b2[ot * 16 + quad * 4 + r];
            // layer3 blocks: blk = (ks*6 + ot)*8 + ((c0+kc)>>5); COUT/16=6
            #pragma unroll 1
            for (int c0 = 0; c0 < 256; c0 += 64) {
                #pragma unroll
                for (int ks = 0; ks < 3; ++ks) {
                    #pragma unroll
                    for (int kc = 0; kc < 64; kc += 32) {
                        short8 af = *(const short8*)(w2b + (size_t)((ks * 6 + ot) * 8 + ((c0 + kc) >> 5)) * 512 + lane * 8);
                        short8 bf = *(const short8*)&h1s[nt * 16 + l15 + ks][c0 + kc + quad * 8];
                        a3 = __builtin_amdgcn_mfma_f32_16x16x32_bf16(af, bf, a3, 0, 0, 0);
                    }
                }
            }
            const int t = t0 + nt * 16 + l15;
            #pragma unroll
            for (int r = 0; r < 4; ++r) {
                int o = ot * 16 + quad * 4 + r;
                float val = a3[r];
                if (o < ZDIM) {
                    mu[(b * ZDIM + o) * TT + t] = val;
                } else {
                    int oc = o - ZDIM;
                    int z  = oc >> 1;
                    float sp = softplus_f(val);
                    if ((oc & 1) == 0) dd[(b * ZDIM + z) * TT + t] = sp + 1.f;
                    else               ss[(b * ZDIM + z) * TT + t] = sp;
                }
            }
        }
    }
}

// ---------------- banded inverse-transpose ----------------
// scale_tril[r,c] = invd[r] * prod_{k=c}^{r-1} t_k (t_k = -s_k/d_k), 0 above diag.
// One 256-thread block per (b,z): 4 waves = 4 row-bands sharing one invd/tt
// load. Ascending product order -> bit-identical to the 1-wave version.
// Write-bound: 268 MB fp32 out, ~43 us floor.
__global__ __launch_bounds__(256)
void tril_kernel(const float* __restrict__ dd, const float* __restrict__ ss,
                 float* __restrict__ out)
{
    __shared__ float invd[TT];
    __shared__ float tt[TT];

    const int bz  = blockIdx.x;
    const int tid = threadIdx.x;

    {
        float d  = dd[bz * TT + tid];
        float s  = ss[bz * TT + tid];
        float iv = 1.0f / d;
        invd[tid] = iv;
        tt[tid]   = -s * iv;
    }
    __syncthreads();

    const int r0 = (tid >> 6) * 64;
    const int c0 = (tid & 63) * 4;

    float p0 = 1.f, p1 = 1.f, p2 = 1.f, p3 = 1.f;
    for (int k = 0; k < r0 - 1; ++k) {
        float tm = tt[k];
        p0 = (k >= c0    ) ? p0 * tm : p0;
        p1 = (k >= c0 + 1) ? p1 * tm : p1;
        p2 = (k >= c0 + 2) ? p2 * tm : p2;
        p3 = (k >= c0 + 3) ? p3 * tm : p3;
    }
    p0 = (c0     < r0) ? p0 : 0.f;
    p1 = (c0 + 1 < r0) ? p1 : 0.f;
    p2 = (c0 + 2 < r0) ? p2 : 0.f;
    p3 = (c0 + 3 < r0) ? p3 : 0.f;

    float* orow = out + (size_t)bz * TT * TT + (size_t)r0 * TT + c0;

    #pragma unroll 2
    for (int r = r0; r < r0 + 64; ++r) {
        float tm = (r > 0) ? tt[r - 1] : 0.0f;
        p0 = (r == c0    ) ? 1.0f : p0 * tm;
        p1 = (r == c0 + 1) ? 1.0f : p1 * tm;
        p2 = (r == c0 + 2) ? 1.0f : p2 * tm;
        p3 = (r == c0 + 3) ? 1.0f : p3 * tm;
        float id = invd[r];
        vf4 v;
        v.x = p0 * id; v.y = p1 * id; v.z = p2 * id; v.w = p3 * id;
        v.x = isfinite(v.x) ? v.x : 0.0f;
        v.y = isfinite(v.y) ? v.y : 0.0f;
        v.z = isfinite(v.z) ? v.z : 0.0f;
        v.w = isfinite(v.w) ? v.w : 0.0f;
        __builtin_nontemporal_store(v, (vf4*)orow);
        orow += TT;
    }
}

extern "C" void kernel_launch(void* const* d_in, const int* in_sizes, int n_in,
                              void* d_out, int out_size, void* d_ws, size_t ws_size,
                              hipStream_t stream)
{
    const float* x  = (const float*)d_in[0];
    const float* W0 = (const float*)d_in[1];
    const float* b0 = (const float*)d_in[2];
    const float* W1 = (const float*)d_in[3];
    const float* b1 = (const float*)d_in[4];
    const float* W2 = (const float*)d_in[5];
    const float* b2 = (const float*)d_in[6];

    float* out = (float*)d_out;
    float* mu  = out;                          // (32,32,256)
    float* st  = out + BB * ZDIM * TT;         // (32,32,256,256)

    // workspace: fp32 dd/ss + bf16 blocked-fragment weights (no intermediates)
    float* dd = (float*)d_ws;                              // 262,144 floats
    float* ss = dd + BB * ZDIM * TT;                       // 262,144 floats
    unsigned short* w0b = (unsigned short*)(ss + BB * ZDIM * TT);  // 3*256*64
    unsigned short* w1b = w0b + 3 * 256 * 64;                      // 3*256*256
    unsigned short* w2b = w1b + 3 * 256 * 256;                     // 3*96*256

    // weight preconvert to blocked fragment order
    wconv_kernel<<<dim3(256), 256, 0, stream>>>(W0, W1, W2, w0b, w1b, w2b);
    // fused conv1+conv2+conv3: 256 blocks (1/CU), 8 waves, 3 barriers
    fused_conv<<<dim3(BB, 8), 512, 0, stream>>>(
        x, w0b, w1b, w2b, b0, b1, b2, mu, dd, ss);
    // banded inverse-transpose, write-bound; 1 block = 4 bands per (b,z)
    tril_kernel<<<dim3(BB * ZDIM), 256, 0, stream>>>(dd, ss, st);
}

// Round 9
// 300.000 us; speedup vs baseline: 1.1585x; 1.0114x over previous
//
#include <hip/hip_runtime.h>
#include <hip/hip_bf16.h>
#include <math.h>

#define BB 32
#define TT 256
#define ZDIM 32

typedef float vf4 __attribute__((ext_vector_type(4)));
typedef short short8 __attribute__((ext_vector_type(8)));
typedef short short4v __attribute__((ext_vector_type(4)));
typedef float f32x4 __attribute__((ext_vector_type(4)));

__device__ __forceinline__ float softplus_f(float v) {
    return fmaxf(v, 0.0f) + log1pf(expf(-fabsf(v)));
}

__device__ __forceinline__ unsigned short f2bf(float f) {
    __hip_bfloat16 h = __float2bfloat16(f);
    return *reinterpret_cast<unsigned short*>(&h);
}

// ---------------- weight preconvert: blocked fragment layout ----------------
// W[o][ci][k] fp32 -> Wb[ks][otile][kch][lane][8] bf16: a wave's A fragment
// for (ks, otile, 32-ci chunk kch) is the contiguous 1 KB block
// Wb + blk*512 + lane*8  (o = otile*16 + (lane&15), ci = kch*32 + (lane>>4)*8 + j).
template<int COUT, int CIN>
__device__ void wconv_frag(const float* __restrict__ W, unsigned short* __restrict__ Wb,
                           int tid, int nthreads)
{
    const int n = 3 * COUT * CIN;
    for (int idx = tid; idx < n; idx += nthreads) {
        int j     = idx & 7;
        int lane  = (idx >> 3) & 63;
        int rest  = idx >> 9;                 // (ks*(COUT/16)+ot)*(CIN/32)+kch
        int kch   = rest % (CIN / 32);
        int rest2 = rest / (CIN / 32);
        int ot    = rest2 % (COUT / 16);
        int ks    = rest2 / (COUT / 16);
        int o  = ot * 16 + (lane & 15);
        int ci = kch * 32 + (lane >> 4) * 8 + j;
        Wb[idx] = f2bf(W[(o * CIN + ci) * 3 + ks]);
    }
}

__global__ __launch_bounds__(256)
void wconv_kernel(const float* __restrict__ W0, const float* __restrict__ W1,
                  const float* __restrict__ W2, unsigned short* __restrict__ w0b,
                  unsigned short* __restrict__ w1b, unsigned short* __restrict__ w2b)
{
    const int tid = blockIdx.x * blockDim.x + threadIdx.x;
    const int nth = gridDim.x * blockDim.x;
    wconv_frag<256, 64>(W0, w0b, tid, nth);
    wconv_frag<256, 256>(W1, w1b, tid, nth);
    wconv_frag<96, 256>(W2, w2b, tid, nth);
}

// ---------------- fused conv1+conv2+conv3, 16-wave ----------------
// ROUND 9: same (b, 32-t) block geometry and LDS plan as rounds 7/8, but
// 1024 threads = 16 waves = 4 waves/SIMD (was 8 waves = 2/SIMD). Each wave
// now owns ONE o-tile (was two) in layers 1-2: per-wave serial {af-load ->
// MFMA} path halves while the SIMD has 2x waves to hide L2/LDS latency.
// af L2 traffic unchanged (1 af/iter/wave); bf LDS reads double (acceptable:
// LDS is the fast resource). Work split is wave-index-only; per-acc MFMA
// order (c0 -> ks -> kc) unchanged -> bit-identical numerics.
// Layouts (m89): A[m=lane&15][ci=quad*8+j], B[ci=quad*8+j][n=lane&15],
// C row = quad*4+reg (o), col = lane&15 (t).
__global__ __launch_bounds__(1024, 1)
void fused_conv(const float* __restrict__ x,
                const unsigned short* __restrict__ w0b,
                const unsigned short* __restrict__ w1b,
                const unsigned short* __restrict__ w2b,
                const float* __restrict__ b0, const float* __restrict__ b1,
                const float* __restrict__ b2,
                float* __restrict__ mu, float* __restrict__ dd,
                float* __restrict__ ss)
{
    constexpr int XPAD = 72;    // 144 B rows (aligned b128 reads)
    constexpr int HPAD = 264;   // 528 B rows (aligned; 4-dw bank shift per row)

    __shared__ __attribute__((aligned(16))) unsigned short xsb[64][XPAD]; // x: [t-(t0-16)][ci]
    __shared__ __attribute__((aligned(16))) unsigned short h0s[48][HPAD]; // h0: [t-(t0-8)][o]
    __shared__ __attribute__((aligned(16))) unsigned short h1s[34][HPAD]; // h1: [t-(t0-1)][o]

    const int b    = blockIdx.x;
    const int t0   = blockIdx.y * 32;
    const int tid  = threadIdx.x;
    const int wv   = tid >> 6;          // 0..15
    const int lane = tid & 63;
    const int l15  = lane & 15;
    const int quad = lane >> 4;

    // ---- stage x: 64 rows [t0-16, t0+48) x 64 ci; waves 0-7 stage 8 rows
    // each (one ci row per lane, f32x4 x2 load). Waves 8-15 pass through.
    if (wv < 8) {
        const int ci = lane;
        const int t8 = t0 - 16 + wv * 8;
        unsigned short v[8];
        if (t8 >= 0 && t8 < TT) {
            const float* xp = x + (size_t)(b * 64 + ci) * TT + t8;
            f32x4 lo = *(const f32x4*)xp;
            f32x4 hi = *(const f32x4*)(xp + 4);
            #pragma unroll
            for (int j = 0; j < 4; ++j) { v[j] = f2bf(lo[j]); v[4 + j] = f2bf(hi[j]); }
        } else {
            #pragma unroll
            for (int j = 0; j < 8; ++j) v[j] = 0;
        }
        #pragma unroll
        for (int j = 0; j < 8; ++j) xsb[wv * 8 + j][ci] = v[j];
    }
    __syncthreads();

    // ---- layer1: wave wv owns o-tile wv, 3 t-frags at t0-8+nt*16.
    // Reads x at t+ks-1 -> xsb row nt*16 + l15 + ks + 7 (range [7,56]).
    {
        f32x4 a1[3];
        {
            f32x4 bv;
            #pragma unroll
            for (int r = 0; r < 4; ++r) bv[r] = b0[wv * 16 + quad * 4 + r];
            #pragma unroll
            for (int nt = 0; nt < 3; ++nt) a1[nt] = bv;
        }
        // layer1 blocks: blk = (ks*16 + ot)*2 + (kc>>5); COUT/16=16, CIN/32=2
        #pragma unroll
        for (int ks = 0; ks < 3; ++ks) {
            #pragma unroll
            for (int kc = 0; kc < 64; kc += 32) {
                short8 af = *(const short8*)(w0b + (size_t)((ks * 16 + wv) * 2 + (kc >> 5)) * 512 + lane * 8);
                #pragma unroll
                for (int nt = 0; nt < 3; ++nt) {
                    short8 bf = *(const short8*)&xsb[nt * 16 + l15 + ks + 7][kc + quad * 8];
                    a1[nt] = __builtin_amdgcn_mfma_f32_16x16x32_bf16(af, bf, a1[nt], 0, 0, 0);
                }
            }
        }
        // h0s write: row p = nt*16+l15 (t = t0-8+p); relu+bf16, masked to zero
        // outside [0,TT) = SAME padding for layer2.
        #pragma unroll
        for (int nt = 0; nt < 3; ++nt) {
            int p = nt * 16 + l15;
            int t = t0 - 8 + p;
            bool ok = (t >= 0) && (t < TT);
            short4v v;
            #pragma unroll
            for (int r = 0; r < 4; ++r)
                v[r] = ok ? (short)f2bf(fmaxf(a1[nt][r], 0.f)) : (short)0;
            *(short4v*)&h0s[p][wv * 16 + quad * 4] = v;
        }
    }
    __syncthreads();

    // ---- layer2: wave wv owns o-tile wv, 3 t-frags at t0 + {-1,15,17}.
    // Reads h0 at t+ks-1 -> h0s row l15 + ks + {6,22,24}[nt] (range [6,41]).
    {
        f32x4 a2[3];
        {
            f32x4 bv;
            #pragma unroll
            for (int r = 0; r < 4; ++r) bv[r] = b1[wv * 16 + quad * 4 + r];
            #pragma unroll
            for (int nt = 0; nt < 3; ++nt) a2[nt] = bv;
        }
        // layer2 blocks: blk = (ks*16 + ot)*8 + ((c0+kc)>>5); CIN/32=8
        #pragma unroll 1
        for (int c0 = 0; c0 < 256; c0 += 64) {
            #pragma unroll
            for (int ks = 0; ks < 3; ++ks) {
                #pragma unroll
                for (int kc = 0; kc < 64; kc += 32) {
                    short8 af = *(const short8*)(w1b + (size_t)((ks * 16 + wv) * 8 + ((c0 + kc) >> 5)) * 512 + lane * 8);
                    #pragma unroll
                    for (int nt = 0; nt < 3; ++nt) {
                        constexpr int F2[3] = {6, 22, 24};
                        short8 bf = *(const short8*)&h0s[F2[nt] + l15 + ks][c0 + kc + quad * 8];
                        a2[nt] = __builtin_amdgcn_mfma_f32_16x16x32_bf16(af, bf, a2[nt], 0, 0, 0);
                    }
                }
            }
        }
        // h1s write: rows {0,16,18}+l15 (t = t0+{-1,15,17}+l15); overlap rows
        // duplicate identical values - benign. Masked padding.
        #pragma unroll
        for (int nt = 0; nt < 3; ++nt) {
            constexpr int P2[3]  = {0, 16, 18};
            constexpr int TO2[3] = {-1, 15, 17};
            int p = P2[nt] + l15;
            int t = t0 + TO2[nt] + l15;
            bool ok = (t >= 0) && (t < TT);
            short4v v;
            #pragma unroll
            for (int r = 0; r < 4; ++r)
                v[r] = ok ? (short)f2bf(fmaxf(a2[nt][r], 0.f)) : (short)0;
            *(short4v*)&h1s[p][wv * 16 + quad * 4] = v;
        }
    }
    __syncthreads();

    // ---- layer3 (stats): 12 tiles (6 o-tiles x 2 t-frags); waves 0-11 take
    // one each, 12-15 idle. Reads h1 at t+ks-1 -> h1s row nt*16 + l15 + ks.
    if (wv < 12) {
        const int ot = wv % 6;
        const int nt = wv / 6;
        f32x4 a3;
        #pragma unroll
        for (int r = 0; r < 4; ++r) a3[r] = b2[ot * 16 + quad * 4 + r];
        // layer3 blocks: blk = (ks*6 + ot)*8 + ((c0+kc)>>5); COUT/16=6
        #pragma unroll 1
        for (int c0 = 0; c0 < 256; c0 += 64) {
            #pragma unroll
            for (int ks = 0; ks < 3; ++ks) {
                #pragma unroll
                for (int kc = 0; kc < 64; kc += 32) {
                    short8 af = *(const short8*)(w2b + (size_t)((ks * 6 + ot) * 8 + ((c0 + kc) >> 5)) * 512 + lane * 8);
                    short8 bf = *(const short8*)&h1s[nt * 16 + l15 + ks][c0 + kc + quad * 8];
                    a3 = __builtin_amdgcn_mfma_f32_16x16x32_bf16(af, bf, a3, 0, 0, 0);
                }
            }
        }
        const int t = t0 + nt * 16 + l15;
        #pragma unroll
        for (int r = 0; r < 4; ++r) {
            int o = ot * 16 + quad * 4 + r;
            float val = a3[r];
            if (o < ZDIM) {
                mu[(b * ZDIM + o) * TT + t] = val;
            } else {
                int oc = o - ZDIM;
                int z  = oc >> 1;
                float sp = softplus_f(val);
                if ((oc & 1) == 0) dd[(b * ZDIM + z) * TT + t] = sp + 1.f;
                else               ss[(b * ZDIM + z) * TT + t] = sp;
            }
        }
    }
}

// ---------------- banded inverse-transpose ----------------
// scale_tril[r,c] = invd[r] * prod_{k=c}^{r-1} t_k (t_k = -s_k/d_k), 0 above diag.
// One 256-thread block per (b,z): 4 waves = 4 row-bands sharing one invd/tt
// load. Ascending product order -> bit-identical to the 1-wave version.
// Write-bound: 268 MB fp32 out, ~43 us floor.
__global__ __launch_bounds__(256)
void tril_kernel(const float* __restrict__ dd, const float* __restrict__ ss,
                 float* __restrict__ out)
{
    __shared__ float invd[TT];
    __shared__ float tt[TT];

    const int bz  = blockIdx.x;
    const int tid = threadIdx.x;

    {
        float d  = dd[bz * TT + tid];
        float s  = ss[bz * TT + tid];
        float iv = 1.0f / d;
        invd[tid] = iv;
        tt[tid]   = -s * iv;
    }
    __syncthreads();

    const int r0 = (tid >> 6) * 64;
    const int c0 = (tid & 63) * 4;

    float p0 = 1.f, p1 = 1.f, p2 = 1.f, p3 = 1.f;
    for (int k = 0; k < r0 - 1; ++k) {
        float tm = tt[k];
        p0 = (k >= c0    ) ? p0 * tm : p0;
        p1 = (k >= c0 + 1) ? p1 * tm : p1;
        p2 = (k >= c0 + 2) ? p2 * tm : p2;
        p3 = (k >= c0 + 3) ? p3 * tm : p3;
    }
    p0 = (c0     < r0) ? p0 : 0.f;
    p1 = (c0 + 1 < r0) ? p1 : 0.f;
    p2 = (c0 + 2 < r0) ? p2 : 0.f;
    p3 = (c0 + 3 < r0) ? p3 : 0.f;

    float* orow = out + (size_t)bz * TT * TT + (size_t)r0 * TT + c0;

    #pragma unroll 2
    for (int r = r0; r < r0 + 64; ++r) {
        float tm = (r > 0) ? tt[r - 1] : 0.0f;
        p0 = (r == c0    ) ? 1.0f : p0 * tm;
        p1 = (r == c0 + 1) ? 1.0f : p1 * tm;
        p2 = (r == c0 + 2) ? 1.0f : p2 * tm;
        p3 = (r == c0 + 3) ? 1.0f : p3 * tm;
        float id = invd[r];
        vf4 v;
        v.x = p0 * id; v.y = p1 * id; v.z = p2 * id; v.w = p3 * id;
        v.x = isfinite(v.x) ? v.x : 0.0f;
        v.y = isfinite(v.y) ? v.y : 0.0f;
        v.z = isfinite(v.z) ? v.z : 0.0f;
        v.w = isfinite(v.w) ? v.w : 0.0f;
        __builtin_nontemporal_store(v, (vf4*)orow);
        orow += TT;
    }
}

extern "C" void kernel_launch(void* const* d_in, const int* in_sizes, int n_in,
                              void* d_out, int out_size, void* d_ws, size_t ws_size,
                              hipStream_t stream)
{
    const float* x  = (const float*)d_in[0];
    const float* W0 = (const float*)d_in[1];
    const float* b0 = (const float*)d_in[2];
    const float* W1 = (const float*)d_in[3];
    const float* b1 = (const float*)d_in[4];
    const float* W2 = (const float*)d_in[5];
    const float* b2 = (const float*)d_in[6];

    float* out = (float*)d_out;
    float* mu  = out;                          // (32,32,256)
    float* st  = out + BB * ZDIM * TT;         // (32,32,256,256)

    // workspace: fp32 dd/ss + bf16 blocked-fragment weights (no intermediates)
    float* dd = (float*)d_ws;                              // 262,144 floats
    float* ss = dd + BB * ZDIM * TT;                       // 262,144 floats
    unsigned short* w0b = (unsigned short*)(ss + BB * ZDIM * TT);  // 3*256*64
    unsigned short* w1b = w0b + 3 * 256 * 64;                      // 3*256*256
    unsigned short* w2b = w1b + 3 * 256 * 256;                     // 3*96*256

    // weight preconvert to blocked fragment order
    wconv_kernel<<<dim3(256), 256, 0, stream>>>(W0, W1, W2, w0b, w1b, w2b);
    // fused conv1+conv2+conv3: 256 blocks (1/CU), 16 waves, 3 barriers
    fused_conv<<<dim3(BB, 8), 1024, 0, stream>>>(
        x, w0b, w1b, w2b, b0, b1, b2, mu, dd, ss);
    // banded inverse-transpose, write-bound; 1 block = 4 bands per (b,z)
    tril_kernel<<<dim3(BB * ZDIM), 256, 0, stream>>>(dd, ss, st);
}